// Round 11
// baseline (190.560 us; speedup 1.0000x reference)
//
#include <hip/hip_runtime.h>
#include <hip/hip_fp16.h>

// GCN 2-layer forward: out = softmax( A_norm @ relu(A_norm @ (x@W1) + b1) @ W2 + b2 )
// A_norm = D^-1/2 (A + I) D^-1/2, edges are col->row (row = target).
//
// R10 -> R11:
//  - degree-rank permutation per bucket (computed in k_sortgemm, O(256)
//    broadcast rank loop): agg1/agg2 waves process degree-similar nodes, so
//    the wave's maxd ~= deg (was E[max of 8 Poisson] ~ 1.5x E[deg] -> ~40% of
//    gather issues were zero-row padding).
//  - k_bin tile 4096 -> 2048 (grid 391 -> 782, ~3 blocks/CU).
// 5 dispatches: memset(relcur) -> bin -> sort+gemm(+perm) -> agg1 -> agg2.

typedef _Float16 f16x8 __attribute__((ext_vector_type(8)));
typedef float f32x4 __attribute__((ext_vector_type(4)));

#define CAPSH 13
#define CAP (1 << CAPSH)          // per-bucket pairbuf/scol capacity

// ---- 1. bin edges into per-bucket fixed slices (coalesced packed runs) -----
__global__ __launch_bounds__(256) void k_bin(const int* __restrict__ row,
                                             const int* __restrict__ col,
                                             int* __restrict__ relcur,
                                             unsigned* __restrict__ pairbuf,
                                             __half* __restrict__ hp,
                                             int E, int nb, int N) {
    __shared__ unsigned items[2048];        // (r&255)<<24 | col
    __shared__ unsigned short bktid[2048];
    __shared__ int cnt[392];
    __shared__ int start0[392];
    __shared__ int cursor[392];
    __shared__ int gbase[392];

    int tid = threadIdx.x;
    int base = blockIdx.x * 2048;
    int m = E - base; if (m > 2048) m = 2048;

    for (int t = tid; t < nb; t += 256) cnt[t] = 0;
    __syncthreads();
    for (int i = tid; i < m; i += 256) atomicAdd(&cnt[row[base + i] >> 8], 1);
    __syncthreads();
    // wave0: exclusive scan of tile counts -> start0, cursor
    if (tid < 64) {
        int lane = tid, running = 0;
        for (int ch = 0; ch < 7; ++ch) {
            int idx = ch * 64 + lane;
            int v = (idx < nb) ? cnt[idx] : 0;
            int s = v;
#pragma unroll
            for (int off = 1; off < 64; off <<= 1) {
                int t = __shfl_up(s, off, 64);
                if (lane >= off) s += t;
            }
            if (idx < nb) { start0[idx] = running + s - v; cursor[idx] = running + s - v; }
            running += __shfl(s, 63, 64);
        }
    }
    __syncthreads();
    for (int i = tid; i < m; i += 256) {
        int r = row[base + i];
        int c = col[base + i];
        int b = r >> 8;
        int pos = atomicAdd(&cursor[b], 1);
        items[pos] = ((unsigned)(r & 255) << 24) | (unsigned)c;
        bktid[pos] = (unsigned short)b;
    }
    __syncthreads();
    // claim global space: bucket b's slice starts at b*CAP
    for (int t = tid; t < nb; t += 256) {
        int cv = cnt[t];
        if (cv > 0) gbase[t] = (t << CAPSH) + atomicAdd(&relcur[t], cv);
    }
    __syncthreads();
    for (int i = tid; i < m; i += 256) {
        int b = bktid[i];
        pairbuf[gbase[b] + (i - start0[b])] = items[i];
    }
    if (blockIdx.x == 0 && tid < 32) ((int*)(hp + (size_t)N * 64))[tid] = 0;  // zero row
}

// ---- 2. per-bucket sort -> scol/offsets/deg/dinv + degree-perm + MFMA gemm -
__global__ __launch_bounds__(256, 4) void k_sortgemm(const unsigned* __restrict__ pairbuf,
                                                     const int* __restrict__ relcur,
                                                     const float* __restrict__ x,
                                                     const float* __restrict__ W1,
                                                     int* __restrict__ scol,
                                                     int* __restrict__ offsets,
                                                     int* __restrict__ deg,
                                                     float* __restrict__ dinv,
                                                     int* __restrict__ pperm,
                                                     __half* __restrict__ hp,
                                                     int N, int nb) {
    __shared__ int cnt[256];     // hist; later reused as sperm
    __shared__ int tmp[256];     // scan; later reused as sdeg
    __shared__ int cur[256];
    __shared__ float sdinv[256];
    int b = blockIdx.x;
    int tid = threadIdx.x;
    int lane = tid & 63, q = lane >> 4, mm = lane & 15;
    // B-frags (W1 fp16), loaded once per block: B[k][n], n=nt*16+mm, k=kk*32+q*8+j
    f16x8 bf[4][2];
#pragma unroll
    for (int nt = 0; nt < 4; ++nt)
#pragma unroll
        for (int kk = 0; kk < 2; ++kk)
#pragma unroll
            for (int j = 0; j < 8; ++j)
                bf[nt][kk][j] = (_Float16)W1[(kk * 32 + q * 8 + j) * 64 + nt * 16 + mm];

    int lo = b << CAPSH;
    int hi = lo + relcur[b];
    int n0 = b << 8;
    int nn = N - n0; if (nn > 256) nn = 256;   // multiple of 16
    cnt[tid] = 0;
    __syncthreads();
    for (int i = lo + tid; i < hi; i += 256)
        atomicAdd(&cnt[pairbuf[i] >> 24], 1);
    __syncthreads();
    int cv = cnt[tid];
    tmp[tid] = cv;
    __syncthreads();
    for (int d = 1; d < 256; d <<= 1) {
        int t = (tid >= d) ? tmp[tid - d] : 0;
        __syncthreads();
        if (tid >= d) tmp[tid] += t;
        __syncthreads();
    }
    int excl = tmp[tid] - cv;
    int n = n0 + tid;
    float dv = rsqrtf((float)(cv + 1));     // +1 self-loop
    if (n < N) { offsets[n] = lo + excl; deg[n] = cv; dinv[n] = dv; }
    sdinv[tid] = dv;
    cur[tid] = lo + excl;
    if (b == 0 && tid == 0) {
        offsets[N] = 0; deg[N] = 0;         // clamped-node entry
        scol[nb << CAPSH] = N;              // sentinel -> zero row
    }
    __syncthreads();
    for (int i = lo + tid; i < hi; i += 256) {
        unsigned it = pairbuf[i];
        int pos = atomicAdd(&cur[it >> 24], 1);
        scol[pos] = (int)(it & 0xFFFFFFu);
    }
    // ---- degree-rank permutation (ties by index) ----
    __syncthreads();
    int myd = (tid < nn) ? cv : 0x7FFFFFFF;
    tmp[tid] = myd;                          // tmp reused as sdeg
    __syncthreads();
    int rank = 0;
    for (int j = 0; j < 256; ++j) {          // LDS broadcast reads
        int dj = tmp[j];
        rank += (dj < myd) || (dj == myd && j < tid);
    }
    cnt[rank] = tid;                         // cnt reused as sperm
    __syncthreads();
    int node = n0 + cnt[tid];
    pperm[n0 + tid] = (node < N) ? node : N;
    // ---- gemm this bucket's nodes (nn is a multiple of 16) ----
    for (int t = (tid >> 6); t < (nn >> 4); t += 4) {
        const float* xrow = x + (size_t)(n0 + t * 16 + mm) * 64;
        float4 u0 = *(const float4*)(xrow + q * 8);
        float4 u1 = *(const float4*)(xrow + q * 8 + 4);
        float4 u2 = *(const float4*)(xrow + 32 + q * 8);
        float4 u3 = *(const float4*)(xrow + 32 + q * 8 + 4);
        f16x8 a0, a1;
        a0[0] = (_Float16)u0.x; a0[1] = (_Float16)u0.y; a0[2] = (_Float16)u0.z; a0[3] = (_Float16)u0.w;
        a0[4] = (_Float16)u1.x; a0[5] = (_Float16)u1.y; a0[6] = (_Float16)u1.z; a0[7] = (_Float16)u1.w;
        a1[0] = (_Float16)u2.x; a1[1] = (_Float16)u2.y; a1[2] = (_Float16)u2.z; a1[3] = (_Float16)u2.w;
        a1[4] = (_Float16)u3.x; a1[5] = (_Float16)u3.y; a1[6] = (_Float16)u3.z; a1[7] = (_Float16)u3.w;
        f32x4 ac0 = {0.f, 0.f, 0.f, 0.f}, ac1 = ac0, ac2 = ac0, ac3 = ac0;
        ac0 = __builtin_amdgcn_mfma_f32_16x16x32_f16(a0, bf[0][0], ac0, 0, 0, 0);
        ac1 = __builtin_amdgcn_mfma_f32_16x16x32_f16(a0, bf[1][0], ac1, 0, 0, 0);
        ac2 = __builtin_amdgcn_mfma_f32_16x16x32_f16(a0, bf[2][0], ac2, 0, 0, 0);
        ac3 = __builtin_amdgcn_mfma_f32_16x16x32_f16(a0, bf[3][0], ac3, 0, 0, 0);
        ac0 = __builtin_amdgcn_mfma_f32_16x16x32_f16(a1, bf[0][1], ac0, 0, 0, 0);
        ac1 = __builtin_amdgcn_mfma_f32_16x16x32_f16(a1, bf[1][1], ac1, 0, 0, 0);
        ac2 = __builtin_amdgcn_mfma_f32_16x16x32_f16(a1, bf[2][1], ac2, 0, 0, 0);
        ac3 = __builtin_amdgcn_mfma_f32_16x16x32_f16(a1, bf[3][1], ac3, 0, 0, 0);
#pragma unroll
        for (int reg = 0; reg < 4; ++reg) {
            int rl = t * 16 + q * 4 + reg;
            float dvv = sdinv[rl];
            __half* dst = hp + (size_t)(n0 + rl) * 64 + mm;
            dst[0]  = __float2half(dvv * ac0[reg]);
            dst[16] = __float2half(dvv * ac1[reg]);
            dst[32] = __float2half(dvv * ac2[reg]);
            dst[48] = __float2half(dvv * ac3[reg]);
        }
    }
}

// ---- 3. layer-1 agg + relu(+b1) + 64->2 projection, fused ------------------
// Wave = 8 degree-similar nodes (via pperm); slot=lane>>3 owns a node,
// chunk=lane&7 owns 16B of its 128B row. 8-deep unrolled gathers.
__global__ __launch_bounds__(256, 4) void k_agg1(const __half* __restrict__ hp,
                                                 const int* __restrict__ offsets,
                                                 const int* __restrict__ deg,
                                                 const int* __restrict__ scol,
                                                 const float* __restrict__ dinv,
                                                 const float* __restrict__ b1,
                                                 const float* __restrict__ W2,
                                                 const int* __restrict__ pperm,
                                                 float2* __restrict__ h2p,
                                                 int N, int SENT, int NP) {
    int lane = threadIdx.x & 63;
    int slot = lane >> 3;
    int chunk = lane & 7;
    int wid = (int)((blockIdx.x * 256 + threadIdx.x) >> 6);
    int idx = wid * 8 + slot;
    int node = (idx < NP) ? pperm[idx] : N;   // node <= N; N = zero row
    int start = offsets[node];
    int dg = deg[node];                       // deg[N] = 0
    int maxd = dg;
#pragma unroll
    for (int s = 8; s <= 32; s <<= 1) {
        int o = __shfl_xor(maxd, s, 64);
        maxd = (o > maxd) ? o : maxd;
    }
    const float4* hp4 = (const float4*)hp;    // row stride = 8 float4
    float4 sr = hp4[(size_t)node * 8 + chunk];  // self term (zero row if pad)
    __half2 acc0 = ((const __half2*)&sr)[0];
    __half2 acc1 = ((const __half2*)&sr)[1];
    __half2 acc2 = ((const __half2*)&sr)[2];
    __half2 acc3 = ((const __half2*)&sr)[3];
    for (int j0 = 0; j0 < maxd; j0 += 8) {
        int c[8];
#pragma unroll
        for (int u = 0; u < 8; ++u)
            c[u] = scol[(j0 + u < dg) ? (start + j0 + u) : SENT];  // SENT -> N
        float4 r[8];
#pragma unroll
        for (int u = 0; u < 8; ++u) r[u] = hp4[(size_t)c[u] * 8 + chunk];
#pragma unroll
        for (int u = 0; u < 8; ++u) {
            const __half2* hh = (const __half2*)&r[u];
            acc0 = __hadd2(acc0, hh[0]); acc1 = __hadd2(acc1, hh[1]);
            acc2 = __hadd2(acc2, hh[2]); acc3 = __hadd2(acc3, hh[3]);
        }
    }
    float af[8];
    { float2 f;
      f = __half22float2(acc0); af[0] = f.x; af[1] = f.y;
      f = __half22float2(acc1); af[2] = f.x; af[3] = f.y;
      f = __half22float2(acc2); af[4] = f.x; af[5] = f.y;
      f = __half22float2(acc3); af[6] = f.x; af[7] = f.y; }
    float dn = dinv[(node < N) ? node : 0];
    float4 b1a = ((const float4*)b1)[chunk * 2];
    float4 b1b = ((const float4*)b1)[chunk * 2 + 1];
    float h1[8];
    h1[0] = fmaxf(fmaf(dn, af[0], b1a.x), 0.f);
    h1[1] = fmaxf(fmaf(dn, af[1], b1a.y), 0.f);
    h1[2] = fmaxf(fmaf(dn, af[2], b1a.z), 0.f);
    h1[3] = fmaxf(fmaf(dn, af[3], b1a.w), 0.f);
    h1[4] = fmaxf(fmaf(dn, af[4], b1b.x), 0.f);
    h1[5] = fmaxf(fmaf(dn, af[5], b1b.y), 0.f);
    h1[6] = fmaxf(fmaf(dn, af[6], b1b.z), 0.f);
    h1[7] = fmaxf(fmaf(dn, af[7], b1b.w), 0.f);
    float p0 = 0.f, p1 = 0.f;
#pragma unroll
    for (int k = 0; k < 4; ++k) {   // float4 = W2 rows {8c+2k, 8c+2k+1}
        float4 w = ((const float4*)W2)[chunk * 4 + k];
        p0 = fmaf(h1[2 * k], w.x, p0); p1 = fmaf(h1[2 * k], w.y, p1);
        p0 = fmaf(h1[2 * k + 1], w.z, p0); p1 = fmaf(h1[2 * k + 1], w.w, p1);
    }
#pragma unroll
    for (int s = 1; s <= 4; s <<= 1) {  // reduce across chunk (bits 0,1,2)
        p0 += __shfl_xor(p0, s, 64);
        p1 += __shfl_xor(p1, s, 64);
    }
    if (chunk == 0 && node < N) h2p[node] = make_float2(dn * p0, dn * p1);  // pre-scaled
}

// ---- 4. layer-2 agg + softmax: 16 lanes per node (degree-similar groups) ---
__global__ __launch_bounds__(256) void k_agg2(const float2* __restrict__ h2p,
                                              const int* __restrict__ offsets,
                                              const int* __restrict__ deg,
                                              const int* __restrict__ scol,
                                              const float* __restrict__ dinv,
                                              const float* __restrict__ b2,
                                              const int* __restrict__ pperm,
                                              float2* __restrict__ out, int N, int NP) {
    int gtid = blockIdx.x * 256 + threadIdx.x;
    int t = gtid >> 4;
    int sub = threadIdx.x & 15;
    if (t >= NP) return;
    int n = pperm[t];
    if (n >= N) return;                       // padding entry
    int start = offsets[n], end = start + deg[n];
    float ax = 0.f, ay = 0.f;
    if (sub == 0) { float2 s = h2p[n]; ax = s.x; ay = s.y; }   // self (pre-scaled)
    for (int j = start + sub; j < end; j += 16) {
        float2 v = h2p[scol[j]];
        ax += v.x; ay += v.y;
    }
#pragma unroll
    for (int s = 1; s <= 8; s <<= 1) {
        ax += __shfl_xor(ax, s, 64);
        ay += __shfl_xor(ay, s, 64);
    }
    if (sub == 0) {
        float dn = dinv[n];
        float l0 = fmaf(dn, ax, b2[0]), l1 = fmaf(dn, ay, b2[1]);
        float m = fmaxf(l0, l1);
        float e0 = __expf(l0 - m), e1 = __expf(l1 - m);
        float inv = 1.0f / (e0 + e1);
        out[n] = make_float2(e0 * inv, e1 * inv);
    }
}

extern "C" void kernel_launch(void* const* d_in, const int* in_sizes, int n_in,
                              void* d_out, int out_size, void* d_ws, size_t ws_size,
                              hipStream_t stream) {
    const float* x  = (const float*)d_in[0];
    const int*   ei = (const int*)d_in[1];
    const float* W1 = (const float*)d_in[2];
    const float* b1 = (const float*)d_in[3];
    const float* W2 = (const float*)d_in[4];
    const float* b2 = (const float*)d_in[5];
    float2* out = (float2*)d_out;

    const int N = in_sizes[0] / 64;     // 100000 (N%16==0, N<2^24)
    const int E = in_sizes[1] / 2;      // 1600000
    const int nb = (N + 255) >> 8;      // 391
    const int NP = nb << 8;             // padded node count (perm length)
    const int SENT = nb << CAPSH;
    const int* row = ei;
    const int* col = ei + E;

    char* p = (char*)d_ws;
    auto alloc = [&](size_t bytes) -> void* {
        void* r = (void*)p;
        p += (bytes + 255) & ~(size_t)255;
        return r;
    };
    int*   relcur  = (int*)alloc((size_t)nb * 4);               // memset exact (R4 lesson)
    int*   offsets = (int*)alloc((size_t)(N + 1) * 4);
    int*   deg     = (int*)alloc((size_t)(N + 1) * 4);
    float* dinv    = (float*)alloc((size_t)N * 4);
    int*   pperm   = (int*)alloc((size_t)NP * 4);
    unsigned* pairbuf = (unsigned*)alloc((size_t)nb * CAP * 4);
    int*   scol    = (int*)alloc(((size_t)nb * CAP + 1) * 4);   // +1 sentinel
    __half* hp     = (__half*)alloc((size_t)(N + 1) * 64 * 2);  // +1 zero row
    float2* h2p    = (float2*)alloc((size_t)N * 8);

    const int nTile = (E + 2047) / 2048;  // 782

    hipMemsetAsync(relcur, 0, (size_t)nb * 4, stream);
    k_bin<<<nTile, 256, 0, stream>>>(row, col, relcur, pairbuf, hp, E, nb, N);
    k_sortgemm<<<nb, 256, 0, stream>>>(pairbuf, relcur, x, W1, scol, offsets, deg, dinv, pperm, hp, N, nb);
    const int nwaves = NP / 8;                       // 8 nodes per wave
    k_agg1<<<(nwaves + 3) / 4, 256, 0, stream>>>(hp, offsets, deg, scol, dinv, b1, W2, pperm, h2p, N, SENT, NP);
    k_agg2<<<(NP * 16 + 255) / 256, 256, 0, stream>>>(h2p, offsets, deg, scol, dinv, b2, pperm, out, N, NP);
}

// Round 12
// 168.806 us; speedup vs baseline: 1.1289x; 1.1289x over previous
//
#include <hip/hip_runtime.h>
#include <hip/hip_fp16.h>

// GCN 2-layer forward: out = softmax( A_norm @ relu(A_norm @ (x@W1) + b1) @ W2 + b2 )
// A_norm = D^-1/2 (A + I) D^-1/2, edges are col->row (row = target).
//
// R11 -> R12: degree-perm REVERTED (regressed 166->191: indirection + lost
// coalescing on offsets/deg/h2p/out; padded gathers were never the cost —
// they hit the L1-hot zero row). Base = R10 (166us). One change: agg1's scol
// loads are SOFTWARE-PIPELINED (preload cs[8]; issue next iter's loads after
// this iter's gathers) so c-load latency overlaps the gather waits.
// 5 dispatches: memset(relcur) -> bin -> sort+gemm -> agg1 -> agg2.

typedef _Float16 f16x8 __attribute__((ext_vector_type(8)));
typedef float f32x4 __attribute__((ext_vector_type(4)));

#define CAPSH 13
#define CAP (1 << CAPSH)          // per-bucket pairbuf/scol capacity

// ---- 1. bin edges into per-bucket fixed slices (coalesced packed runs) -----
__global__ __launch_bounds__(256) void k_bin(const int* __restrict__ row,
                                             const int* __restrict__ col,
                                             int* __restrict__ relcur,
                                             unsigned* __restrict__ pairbuf,
                                             __half* __restrict__ hp,
                                             int E, int nb, int N) {
    __shared__ unsigned items[4096];        // (r&255)<<24 | col
    __shared__ unsigned short bktid[4096];
    __shared__ int cnt[392];
    __shared__ int start0[392];
    __shared__ int cursor[392];
    __shared__ int gbase[392];

    int tid = threadIdx.x;
    int base = blockIdx.x * 4096;
    int m = E - base; if (m > 4096) m = 4096;

    for (int t = tid; t < nb; t += 256) cnt[t] = 0;
    __syncthreads();
    for (int i = tid; i < m; i += 256) atomicAdd(&cnt[row[base + i] >> 8], 1);
    __syncthreads();
    // wave0: exclusive scan of tile counts -> start0, cursor
    if (tid < 64) {
        int lane = tid, running = 0;
        for (int ch = 0; ch < 7; ++ch) {
            int idx = ch * 64 + lane;
            int v = (idx < nb) ? cnt[idx] : 0;
            int s = v;
#pragma unroll
            for (int off = 1; off < 64; off <<= 1) {
                int t = __shfl_up(s, off, 64);
                if (lane >= off) s += t;
            }
            if (idx < nb) { start0[idx] = running + s - v; cursor[idx] = running + s - v; }
            running += __shfl(s, 63, 64);
        }
    }
    __syncthreads();
    for (int i = tid; i < m; i += 256) {
        int r = row[base + i];
        int c = col[base + i];
        int b = r >> 8;
        int pos = atomicAdd(&cursor[b], 1);
        items[pos] = ((unsigned)(r & 255) << 24) | (unsigned)c;
        bktid[pos] = (unsigned short)b;
    }
    __syncthreads();
    // claim global space: bucket b's slice starts at b*CAP
    for (int t = tid; t < nb; t += 256) {
        int cv = cnt[t];
        if (cv > 0) gbase[t] = (t << CAPSH) + atomicAdd(&relcur[t], cv);
    }
    __syncthreads();
    for (int i = tid; i < m; i += 256) {
        int b = bktid[i];
        pairbuf[gbase[b] + (i - start0[b])] = items[i];
    }
    if (blockIdx.x == 0 && tid < 32) ((int*)(hp + (size_t)N * 64))[tid] = 0;  // zero row
}

// ---- 2. per-bucket counting sort -> scol/offsets/deg/dinv, + MFMA gemm -----
// One block per bucket. After the sort, the same block computes
// hp[n] = fp16(dinv[n] * x[n]@W1) for its 256 nodes (dinv via LDS).
__global__ __launch_bounds__(256, 4) void k_sortgemm(const unsigned* __restrict__ pairbuf,
                                                     const int* __restrict__ relcur,
                                                     const float* __restrict__ x,
                                                     const float* __restrict__ W1,
                                                     int* __restrict__ scol,
                                                     int* __restrict__ offsets,
                                                     int* __restrict__ deg,
                                                     float* __restrict__ dinv,
                                                     __half* __restrict__ hp,
                                                     int N, int nb) {
    __shared__ int cnt[256];
    __shared__ int tmp[256];
    __shared__ int cur[256];
    __shared__ float sdinv[256];
    int b = blockIdx.x;
    int tid = threadIdx.x;
    int lane = tid & 63, q = lane >> 4, mm = lane & 15;
    // B-frags (W1 fp16), loaded once per block: B[k][n], n=nt*16+mm, k=kk*32+q*8+j
    f16x8 bf[4][2];
#pragma unroll
    for (int nt = 0; nt < 4; ++nt)
#pragma unroll
        for (int kk = 0; kk < 2; ++kk)
#pragma unroll
            for (int j = 0; j < 8; ++j)
                bf[nt][kk][j] = (_Float16)W1[(kk * 32 + q * 8 + j) * 64 + nt * 16 + mm];

    int lo = b << CAPSH;
    int hi = lo + relcur[b];
    cnt[tid] = 0;
    __syncthreads();
    for (int i = lo + tid; i < hi; i += 256)
        atomicAdd(&cnt[pairbuf[i] >> 24], 1);
    __syncthreads();
    int cv = cnt[tid];
    tmp[tid] = cv;
    __syncthreads();
    for (int d = 1; d < 256; d <<= 1) {
        int t = (tid >= d) ? tmp[tid - d] : 0;
        __syncthreads();
        if (tid >= d) tmp[tid] += t;
        __syncthreads();
    }
    int excl = tmp[tid] - cv;
    int n = (b << 8) + tid;
    float dv = rsqrtf((float)(cv + 1));     // +1 self-loop
    if (n < N) { offsets[n] = lo + excl; deg[n] = cv; dinv[n] = dv; }
    sdinv[tid] = dv;
    cur[tid] = lo + excl;
    if (b == 0 && tid == 0) {
        offsets[N] = 0; deg[N] = 0;         // clamped-node entry
        scol[nb << CAPSH] = N;              // sentinel -> zero row
    }
    __syncthreads();
    for (int i = lo + tid; i < hi; i += 256) {
        unsigned it = pairbuf[i];
        int pos = atomicAdd(&cur[it >> 24], 1);
        scol[pos] = (int)(it & 0xFFFFFFu);
    }
    __syncthreads();
    // gemm this bucket's nodes (nn is a multiple of 16)
    int n0 = b << 8;
    int nn = N - n0; if (nn > 256) nn = 256;
    for (int t = (tid >> 6); t < (nn >> 4); t += 4) {
        const float* xrow = x + (size_t)(n0 + t * 16 + mm) * 64;
        float4 u0 = *(const float4*)(xrow + q * 8);
        float4 u1 = *(const float4*)(xrow + q * 8 + 4);
        float4 u2 = *(const float4*)(xrow + 32 + q * 8);
        float4 u3 = *(const float4*)(xrow + 32 + q * 8 + 4);
        f16x8 a0, a1;
        a0[0] = (_Float16)u0.x; a0[1] = (_Float16)u0.y; a0[2] = (_Float16)u0.z; a0[3] = (_Float16)u0.w;
        a0[4] = (_Float16)u1.x; a0[5] = (_Float16)u1.y; a0[6] = (_Float16)u1.z; a0[7] = (_Float16)u1.w;
        a1[0] = (_Float16)u2.x; a1[1] = (_Float16)u2.y; a1[2] = (_Float16)u2.z; a1[3] = (_Float16)u2.w;
        a1[4] = (_Float16)u3.x; a1[5] = (_Float16)u3.y; a1[6] = (_Float16)u3.z; a1[7] = (_Float16)u3.w;
        f32x4 ac0 = {0.f, 0.f, 0.f, 0.f}, ac1 = ac0, ac2 = ac0, ac3 = ac0;
        ac0 = __builtin_amdgcn_mfma_f32_16x16x32_f16(a0, bf[0][0], ac0, 0, 0, 0);
        ac1 = __builtin_amdgcn_mfma_f32_16x16x32_f16(a0, bf[1][0], ac1, 0, 0, 0);
        ac2 = __builtin_amdgcn_mfma_f32_16x16x32_f16(a0, bf[2][0], ac2, 0, 0, 0);
        ac3 = __builtin_amdgcn_mfma_f32_16x16x32_f16(a0, bf[3][0], ac3, 0, 0, 0);
        ac0 = __builtin_amdgcn_mfma_f32_16x16x32_f16(a1, bf[0][1], ac0, 0, 0, 0);
        ac1 = __builtin_amdgcn_mfma_f32_16x16x32_f16(a1, bf[1][1], ac1, 0, 0, 0);
        ac2 = __builtin_amdgcn_mfma_f32_16x16x32_f16(a1, bf[2][1], ac2, 0, 0, 0);
        ac3 = __builtin_amdgcn_mfma_f32_16x16x32_f16(a1, bf[3][1], ac3, 0, 0, 0);
#pragma unroll
        for (int reg = 0; reg < 4; ++reg) {
            int rl = t * 16 + q * 4 + reg;
            float dvv = sdinv[rl];
            __half* dst = hp + (size_t)(n0 + rl) * 64 + mm;
            dst[0]  = __float2half(dvv * ac0[reg]);
            dst[16] = __float2half(dvv * ac1[reg]);
            dst[32] = __float2half(dvv * ac2[reg]);
            dst[48] = __float2half(dvv * ac3[reg]);
        }
    }
}

// ---- 3. layer-1 agg + relu(+b1) + 64->2 projection, fused ------------------
// Wave = 8 nodes; slot=lane>>3 owns a node, chunk=lane&7 owns 16B of its row.
// scol loads SOFTWARE-PIPELINED: next iteration's 8 c-loads issue right after
// this iteration's gathers, so their latency overlaps the gather waits.
__global__ __launch_bounds__(256, 4) void k_agg1(const __half* __restrict__ hp,
                                                 const int* __restrict__ offsets,
                                                 const int* __restrict__ deg,
                                                 const int* __restrict__ scol,
                                                 const float* __restrict__ dinv,
                                                 const float* __restrict__ b1,
                                                 const float* __restrict__ W2,
                                                 float2* __restrict__ h2p,
                                                 int N, int SENT) {
    int lane = threadIdx.x & 63;
    int slot = lane >> 3;
    int chunk = lane & 7;
    int wid = (int)((blockIdx.x * 256 + threadIdx.x) >> 6);
    int n = wid * 8 + slot;
    int nc = (n < N) ? n : N;                 // row N of hp is the zero row
    int start = offsets[nc];
    int dg = deg[nc];                         // deg[N] = 0
    int maxd = dg;
#pragma unroll
    for (int s = 8; s <= 32; s <<= 1) {
        int o = __shfl_xor(maxd, s, 64);
        maxd = (o > maxd) ? o : maxd;
    }
    const float4* hp4 = (const float4*)hp;    // row stride = 8 float4
    float4 sr = hp4[(size_t)nc * 8 + chunk];  // self term
    __half2 acc0 = ((const __half2*)&sr)[0];
    __half2 acc1 = ((const __half2*)&sr)[1];
    __half2 acc2 = ((const __half2*)&sr)[2];
    __half2 acc3 = ((const __half2*)&sr)[3];
    // prologue: c-loads for iteration 0
    int cs[8];
#pragma unroll
    for (int u = 0; u < 8; ++u)
        cs[u] = scol[(u < dg) ? (start + u) : SENT];          // SENT -> N (zero row)
    for (int j0 = 0; j0 < maxd; j0 += 8) {
        float4 r[8];
#pragma unroll
        for (int u = 0; u < 8; ++u) r[u] = hp4[(size_t)cs[u] * 8 + chunk];
        // issue NEXT iteration's c-loads while gathers are in flight
        int j1 = j0 + 8;
        int cn[8];
#pragma unroll
        for (int u = 0; u < 8; ++u)
            cn[u] = scol[(j1 + u < dg) ? (start + j1 + u) : SENT];
#pragma unroll
        for (int u = 0; u < 8; ++u) {
            const __half2* hh = (const __half2*)&r[u];
            acc0 = __hadd2(acc0, hh[0]); acc1 = __hadd2(acc1, hh[1]);
            acc2 = __hadd2(acc2, hh[2]); acc3 = __hadd2(acc3, hh[3]);
        }
#pragma unroll
        for (int u = 0; u < 8; ++u) cs[u] = cn[u];
    }
    float af[8];
    { float2 f;
      f = __half22float2(acc0); af[0] = f.x; af[1] = f.y;
      f = __half22float2(acc1); af[2] = f.x; af[3] = f.y;
      f = __half22float2(acc2); af[4] = f.x; af[5] = f.y;
      f = __half22float2(acc3); af[6] = f.x; af[7] = f.y; }
    float dn = dinv[(n < N) ? n : (N - 1)];
    float4 b1a = ((const float4*)b1)[chunk * 2];
    float4 b1b = ((const float4*)b1)[chunk * 2 + 1];
    float h1[8];
    h1[0] = fmaxf(fmaf(dn, af[0], b1a.x), 0.f);
    h1[1] = fmaxf(fmaf(dn, af[1], b1a.y), 0.f);
    h1[2] = fmaxf(fmaf(dn, af[2], b1a.z), 0.f);
    h1[3] = fmaxf(fmaf(dn, af[3], b1a.w), 0.f);
    h1[4] = fmaxf(fmaf(dn, af[4], b1b.x), 0.f);
    h1[5] = fmaxf(fmaf(dn, af[5], b1b.y), 0.f);
    h1[6] = fmaxf(fmaf(dn, af[6], b1b.z), 0.f);
    h1[7] = fmaxf(fmaf(dn, af[7], b1b.w), 0.f);
    float p0 = 0.f, p1 = 0.f;
#pragma unroll
    for (int k = 0; k < 4; ++k) {   // float4 = W2 rows {8c+2k, 8c+2k+1}
        float4 w = ((const float4*)W2)[chunk * 4 + k];
        p0 = fmaf(h1[2 * k], w.x, p0); p1 = fmaf(h1[2 * k], w.y, p1);
        p0 = fmaf(h1[2 * k + 1], w.z, p0); p1 = fmaf(h1[2 * k + 1], w.w, p1);
    }
#pragma unroll
    for (int s = 1; s <= 4; s <<= 1) {  // reduce across chunk (bits 0,1,2)
        p0 += __shfl_xor(p0, s, 64);
        p1 += __shfl_xor(p1, s, 64);
    }
    if (chunk == 0 && n < N) h2p[n] = make_float2(dn * p0, dn * p1);  // pre-scaled
}

// ---- 4. layer-2 agg + softmax: 16 lanes per node ---------------------------
__global__ __launch_bounds__(256) void k_agg2(const float2* __restrict__ h2p,
                                              const int* __restrict__ offsets,
                                              const int* __restrict__ deg,
                                              const int* __restrict__ scol,
                                              const float* __restrict__ dinv,
                                              const float* __restrict__ b2,
                                              float2* __restrict__ out, int N) {
    int gtid = blockIdx.x * 256 + threadIdx.x;
    int n = gtid >> 4;
    int sub = threadIdx.x & 15;
    if (n >= N) return;
    int start = offsets[n], end = start + deg[n];
    float ax = 0.f, ay = 0.f;
    if (sub == 0) { float2 s = h2p[n]; ax = s.x; ay = s.y; }   // self (pre-scaled)
    for (int j = start + sub; j < end; j += 16) {
        float2 v = h2p[scol[j]];
        ax += v.x; ay += v.y;
    }
#pragma unroll
    for (int s = 1; s <= 8; s <<= 1) {
        ax += __shfl_xor(ax, s, 64);
        ay += __shfl_xor(ay, s, 64);
    }
    if (sub == 0) {
        float dn = dinv[n];
        float l0 = fmaf(dn, ax, b2[0]), l1 = fmaf(dn, ay, b2[1]);
        float m = fmaxf(l0, l1);
        float e0 = __expf(l0 - m), e1 = __expf(l1 - m);
        float inv = 1.0f / (e0 + e1);
        out[n] = make_float2(e0 * inv, e1 * inv);
    }
}

extern "C" void kernel_launch(void* const* d_in, const int* in_sizes, int n_in,
                              void* d_out, int out_size, void* d_ws, size_t ws_size,
                              hipStream_t stream) {
    const float* x  = (const float*)d_in[0];
    const int*   ei = (const int*)d_in[1];
    const float* W1 = (const float*)d_in[2];
    const float* b1 = (const float*)d_in[3];
    const float* W2 = (const float*)d_in[4];
    const float* b2 = (const float*)d_in[5];
    float2* out = (float2*)d_out;

    const int N = in_sizes[0] / 64;     // 100000 (N%16==0, N<2^24)
    const int E = in_sizes[1] / 2;      // 1600000
    const int nb = (N + 255) >> 8;      // 391
    const int SENT = nb << CAPSH;
    const int* row = ei;
    const int* col = ei + E;

    char* p = (char*)d_ws;
    auto alloc = [&](size_t bytes) -> void* {
        void* r = (void*)p;
        p += (bytes + 255) & ~(size_t)255;
        return r;
    };
    int*   relcur  = (int*)alloc((size_t)nb * 4);               // memset exact (R4 lesson)
    int*   offsets = (int*)alloc((size_t)(N + 1) * 4);
    int*   deg     = (int*)alloc((size_t)(N + 1) * 4);
    float* dinv    = (float*)alloc((size_t)N * 4);
    unsigned* pairbuf = (unsigned*)alloc((size_t)nb * CAP * 4);
    int*   scol    = (int*)alloc(((size_t)nb * CAP + 1) * 4);   // +1 sentinel
    __half* hp     = (__half*)alloc((size_t)(N + 1) * 64 * 2);  // +1 zero row
    float2* h2p    = (float2*)alloc((size_t)N * 8);

    const int nTile = (E + 4095) / 4096;  // 391

    hipMemsetAsync(relcur, 0, (size_t)nb * 4, stream);
    k_bin<<<nTile, 256, 0, stream>>>(row, col, relcur, pairbuf, hp, E, nb, N);
    k_sortgemm<<<nb, 256, 0, stream>>>(pairbuf, relcur, x, W1, scol, offsets, deg, dinv, hp, N, nb);
    const int nwaves = (N + 7) / 8;                  // 8 nodes per wave
    k_agg1<<<(nwaves + 3) / 4, 256, 0, stream>>>(hp, offsets, deg, scol, dinv, b1, W2, h2p, N, SENT);
    k_agg2<<<(N * 16 + 255) / 256, 256, 0, stream>>>(h2p, offsets, deg, scol, dinv, b2, out, N);
}

// Round 13
// 164.570 us; speedup vs baseline: 1.1579x; 1.0257x over previous
//
#include <hip/hip_runtime.h>
#include <hip/hip_fp16.h>

// GCN 2-layer forward: out = softmax( A_norm @ relu(A_norm @ (x@W1) + b1) @ W2 + b2 )
// A_norm = D^-1/2 (A + I) D^-1/2, edges are col->row (row = target).
//
// R12 -> R13: scol pipelining was neutral (agg1 is MLP-saturated) — agg1
// reverted to the R10 form. This round: 128-NODE BUCKETS (nb=782). sortgemm
// was 391 blocks = 1.5/CU (half the CUs idle through its sort+MFMA work);
// 782 blocks ~= 3/CU halves its critical path. k_bin LDS arrays grow to 784
// entries (36.8KB, still fine); pack (r&127)<<24|col; CAP=4096 (mean 2046).
// 5 dispatches: memset(relcur) -> bin -> sort+gemm -> agg1 -> agg2.

typedef _Float16 f16x8 __attribute__((ext_vector_type(8)));
typedef float f32x4 __attribute__((ext_vector_type(4)));

#define CAPSH 12
#define CAP (1 << CAPSH)          // per-bucket pairbuf/scol capacity
#define NBK 784                   // LDS array size (>= nb = 782)

// ---- 1. bin edges into per-bucket fixed slices (coalesced packed runs) -----
__global__ __launch_bounds__(256) void k_bin(const int* __restrict__ row,
                                             const int* __restrict__ col,
                                             int* __restrict__ relcur,
                                             unsigned* __restrict__ pairbuf,
                                             __half* __restrict__ hp,
                                             int E, int nb, int N) {
    __shared__ unsigned items[4096];        // (r&127)<<24 | col
    __shared__ unsigned short bktid[4096];
    __shared__ int cnt[NBK];
    __shared__ int start0[NBK];
    __shared__ int cursor[NBK];
    __shared__ int gbase[NBK];

    int tid = threadIdx.x;
    int base = blockIdx.x * 4096;
    int m = E - base; if (m > 4096) m = 4096;

    for (int t = tid; t < nb; t += 256) cnt[t] = 0;
    __syncthreads();
    for (int i = tid; i < m; i += 256) atomicAdd(&cnt[row[base + i] >> 7], 1);
    __syncthreads();
    // wave0: exclusive scan of tile counts -> start0, cursor (13 chunks of 64)
    if (tid < 64) {
        int lane = tid, running = 0;
        for (int ch = 0; ch < 13; ++ch) {
            int idx = ch * 64 + lane;
            int v = (idx < nb) ? cnt[idx] : 0;
            int s = v;
#pragma unroll
            for (int off = 1; off < 64; off <<= 1) {
                int t = __shfl_up(s, off, 64);
                if (lane >= off) s += t;
            }
            if (idx < nb) { start0[idx] = running + s - v; cursor[idx] = running + s - v; }
            running += __shfl(s, 63, 64);
        }
    }
    __syncthreads();
    for (int i = tid; i < m; i += 256) {
        int r = row[base + i];
        int c = col[base + i];
        int b = r >> 7;
        int pos = atomicAdd(&cursor[b], 1);
        items[pos] = ((unsigned)(r & 127) << 24) | (unsigned)c;
        bktid[pos] = (unsigned short)b;
    }
    __syncthreads();
    // claim global space: bucket b's slice starts at b*CAP
    for (int t = tid; t < nb; t += 256) {
        int cv = cnt[t];
        if (cv > 0) gbase[t] = (t << CAPSH) + atomicAdd(&relcur[t], cv);
    }
    __syncthreads();
    for (int i = tid; i < m; i += 256) {
        int b = bktid[i];
        pairbuf[gbase[b] + (i - start0[b])] = items[i];
    }
    if (blockIdx.x == 0 && tid < 32) ((int*)(hp + (size_t)N * 64))[tid] = 0;  // zero row
}

// ---- 2. per-bucket (128 nodes) counting sort + MFMA gemm -------------------
// One block per bucket: sort its <=~2300 edges, emit scol/offsets/deg/dinv,
// then compute hp[n] = fp16(dinv[n] * x[n]@W1) for its 128 nodes.
__global__ __launch_bounds__(256, 4) void k_sortgemm(const unsigned* __restrict__ pairbuf,
                                                     const int* __restrict__ relcur,
                                                     const float* __restrict__ x,
                                                     const float* __restrict__ W1,
                                                     int* __restrict__ scol,
                                                     int* __restrict__ offsets,
                                                     int* __restrict__ deg,
                                                     float* __restrict__ dinv,
                                                     __half* __restrict__ hp,
                                                     int N, int nb) {
    __shared__ int cnt[256];      // [128..255] stay 0
    __shared__ int tmp[256];
    __shared__ int cur[256];
    __shared__ float sdinv[128];
    int b = blockIdx.x;
    int tid = threadIdx.x;
    int lane = tid & 63, q = lane >> 4, mm = lane & 15;
    // B-frags (W1 fp16), loaded once per block: B[k][n], n=nt*16+mm, k=kk*32+q*8+j
    f16x8 bf[4][2];
#pragma unroll
    for (int nt = 0; nt < 4; ++nt)
#pragma unroll
        for (int kk = 0; kk < 2; ++kk)
#pragma unroll
            for (int j = 0; j < 8; ++j)
                bf[nt][kk][j] = (_Float16)W1[(kk * 32 + q * 8 + j) * 64 + nt * 16 + mm];

    int lo = b << CAPSH;
    int hi = lo + relcur[b];
    cnt[tid] = 0;
    __syncthreads();
    for (int i = lo + tid; i < hi; i += 256)
        atomicAdd(&cnt[pairbuf[i] >> 24], 1);      // values in [0,128)
    __syncthreads();
    int cv = cnt[tid];
    tmp[tid] = cv;
    __syncthreads();
    for (int d = 1; d < 256; d <<= 1) {
        int t = (tid >= d) ? tmp[tid - d] : 0;
        __syncthreads();
        if (tid >= d) tmp[tid] += t;
        __syncthreads();
    }
    int excl = tmp[tid] - cv;
    int n0 = b << 7;
    if (tid < 128) {
        int n = n0 + tid;
        float dv = rsqrtf((float)(cv + 1));        // +1 self-loop
        if (n < N) { offsets[n] = lo + excl; deg[n] = cv; dinv[n] = dv; }
        sdinv[tid] = dv;
    }
    cur[tid] = lo + excl;
    if (b == 0 && tid == 0) {
        offsets[N] = 0; deg[N] = 0;                // clamped-node entry
        scol[nb << CAPSH] = N;                     // sentinel -> zero row
    }
    __syncthreads();
    for (int i = lo + tid; i < hi; i += 256) {
        unsigned it = pairbuf[i];
        int pos = atomicAdd(&cur[it >> 24], 1);
        scol[pos] = (int)(it & 0xFFFFFFu);
    }
    __syncthreads();
    // gemm this bucket's nodes (nn = 128 or 32 for the last bucket; %16==0)
    int nn = N - n0; if (nn > 128) nn = 128;
    for (int t = (tid >> 6); t < (nn >> 4); t += 4) {
        const float* xrow = x + (size_t)(n0 + t * 16 + mm) * 64;
        float4 u0 = *(const float4*)(xrow + q * 8);
        float4 u1 = *(const float4*)(xrow + q * 8 + 4);
        float4 u2 = *(const float4*)(xrow + 32 + q * 8);
        float4 u3 = *(const float4*)(xrow + 32 + q * 8 + 4);
        f16x8 a0, a1;
        a0[0] = (_Float16)u0.x; a0[1] = (_Float16)u0.y; a0[2] = (_Float16)u0.z; a0[3] = (_Float16)u0.w;
        a0[4] = (_Float16)u1.x; a0[5] = (_Float16)u1.y; a0[6] = (_Float16)u1.z; a0[7] = (_Float16)u1.w;
        a1[0] = (_Float16)u2.x; a1[1] = (_Float16)u2.y; a1[2] = (_Float16)u2.z; a1[3] = (_Float16)u2.w;
        a1[4] = (_Float16)u3.x; a1[5] = (_Float16)u3.y; a1[6] = (_Float16)u3.z; a1[7] = (_Float16)u3.w;
        f32x4 ac0 = {0.f, 0.f, 0.f, 0.f}, ac1 = ac0, ac2 = ac0, ac3 = ac0;
        ac0 = __builtin_amdgcn_mfma_f32_16x16x32_f16(a0, bf[0][0], ac0, 0, 0, 0);
        ac1 = __builtin_amdgcn_mfma_f32_16x16x32_f16(a0, bf[1][0], ac1, 0, 0, 0);
        ac2 = __builtin_amdgcn_mfma_f32_16x16x32_f16(a0, bf[2][0], ac2, 0, 0, 0);
        ac3 = __builtin_amdgcn_mfma_f32_16x16x32_f16(a0, bf[3][0], ac3, 0, 0, 0);
        ac0 = __builtin_amdgcn_mfma_f32_16x16x32_f16(a1, bf[0][1], ac0, 0, 0, 0);
        ac1 = __builtin_amdgcn_mfma_f32_16x16x32_f16(a1, bf[1][1], ac1, 0, 0, 0);
        ac2 = __builtin_amdgcn_mfma_f32_16x16x32_f16(a1, bf[2][1], ac2, 0, 0, 0);
        ac3 = __builtin_amdgcn_mfma_f32_16x16x32_f16(a1, bf[3][1], ac3, 0, 0, 0);
#pragma unroll
        for (int reg = 0; reg < 4; ++reg) {
            int rl = t * 16 + q * 4 + reg;
            float dvv = sdinv[rl];
            __half* dst = hp + (size_t)(n0 + rl) * 64 + mm;
            dst[0]  = __float2half(dvv * ac0[reg]);
            dst[16] = __float2half(dvv * ac1[reg]);
            dst[32] = __float2half(dvv * ac2[reg]);
            dst[48] = __float2half(dvv * ac3[reg]);
        }
    }
}

// ---- 3. layer-1 agg + relu(+b1) + 64->2 projection, fused (R10 form) -------
// Wave = 8 nodes; slot=lane>>3 owns a node, chunk=lane&7 owns 16B of its row.
// 8-deep unrolled gathers (8 scol loads + 8 row gathers in flight per slot).
__global__ __launch_bounds__(256, 4) void k_agg1(const __half* __restrict__ hp,
                                                 const int* __restrict__ offsets,
                                                 const int* __restrict__ deg,
                                                 const int* __restrict__ scol,
                                                 const float* __restrict__ dinv,
                                                 const float* __restrict__ b1,
                                                 const float* __restrict__ W2,
                                                 float2* __restrict__ h2p,
                                                 int N, int SENT) {
    int lane = threadIdx.x & 63;
    int slot = lane >> 3;
    int chunk = lane & 7;
    int wid = (int)((blockIdx.x * 256 + threadIdx.x) >> 6);
    int n = wid * 8 + slot;
    int nc = (n < N) ? n : N;                 // row N of hp is the zero row
    int start = offsets[nc];
    int dg = deg[nc];                         // deg[N] = 0
    int maxd = dg;
#pragma unroll
    for (int s = 8; s <= 32; s <<= 1) {
        int o = __shfl_xor(maxd, s, 64);
        maxd = (o > maxd) ? o : maxd;
    }
    const float4* hp4 = (const float4*)hp;    // row stride = 8 float4
    float4 sr = hp4[(size_t)nc * 8 + chunk];  // self term
    __half2 acc0 = ((const __half2*)&sr)[0];
    __half2 acc1 = ((const __half2*)&sr)[1];
    __half2 acc2 = ((const __half2*)&sr)[2];
    __half2 acc3 = ((const __half2*)&sr)[3];
    for (int j0 = 0; j0 < maxd; j0 += 8) {
        int c[8];
#pragma unroll
        for (int u = 0; u < 8; ++u)
            c[u] = scol[(j0 + u < dg) ? (start + j0 + u) : SENT];  // SENT -> N
        float4 r[8];
#pragma unroll
        for (int u = 0; u < 8; ++u) r[u] = hp4[(size_t)c[u] * 8 + chunk];
#pragma unroll
        for (int u = 0; u < 8; ++u) {
            const __half2* hh = (const __half2*)&r[u];
            acc0 = __hadd2(acc0, hh[0]); acc1 = __hadd2(acc1, hh[1]);
            acc2 = __hadd2(acc2, hh[2]); acc3 = __hadd2(acc3, hh[3]);
        }
    }
    float af[8];
    { float2 f;
      f = __half22float2(acc0); af[0] = f.x; af[1] = f.y;
      f = __half22float2(acc1); af[2] = f.x; af[3] = f.y;
      f = __half22float2(acc2); af[4] = f.x; af[5] = f.y;
      f = __half22float2(acc3); af[6] = f.x; af[7] = f.y; }
    float dn = dinv[(n < N) ? n : (N - 1)];
    float4 b1a = ((const float4*)b1)[chunk * 2];
    float4 b1b = ((const float4*)b1)[chunk * 2 + 1];
    float h1[8];
    h1[0] = fmaxf(fmaf(dn, af[0], b1a.x), 0.f);
    h1[1] = fmaxf(fmaf(dn, af[1], b1a.y), 0.f);
    h1[2] = fmaxf(fmaf(dn, af[2], b1a.z), 0.f);
    h1[3] = fmaxf(fmaf(dn, af[3], b1a.w), 0.f);
    h1[4] = fmaxf(fmaf(dn, af[4], b1b.x), 0.f);
    h1[5] = fmaxf(fmaf(dn, af[5], b1b.y), 0.f);
    h1[6] = fmaxf(fmaf(dn, af[6], b1b.z), 0.f);
    h1[7] = fmaxf(fmaf(dn, af[7], b1b.w), 0.f);
    float p0 = 0.f, p1 = 0.f;
#pragma unroll
    for (int k = 0; k < 4; ++k) {   // float4 = W2 rows {8c+2k, 8c+2k+1}
        float4 w = ((const float4*)W2)[chunk * 4 + k];
        p0 = fmaf(h1[2 * k], w.x, p0); p1 = fmaf(h1[2 * k], w.y, p1);
        p0 = fmaf(h1[2 * k + 1], w.z, p0); p1 = fmaf(h1[2 * k + 1], w.w, p1);
    }
#pragma unroll
    for (int s = 1; s <= 4; s <<= 1) {  // reduce across chunk (bits 0,1,2)
        p0 += __shfl_xor(p0, s, 64);
        p1 += __shfl_xor(p1, s, 64);
    }
    if (chunk == 0 && n < N) h2p[n] = make_float2(dn * p0, dn * p1);  // pre-scaled
}

// ---- 4. layer-2 agg + softmax: 16 lanes per node ---------------------------
__global__ __launch_bounds__(256) void k_agg2(const float2* __restrict__ h2p,
                                              const int* __restrict__ offsets,
                                              const int* __restrict__ deg,
                                              const int* __restrict__ scol,
                                              const float* __restrict__ dinv,
                                              const float* __restrict__ b2,
                                              float2* __restrict__ out, int N) {
    int gtid = blockIdx.x * 256 + threadIdx.x;
    int n = gtid >> 4;
    int sub = threadIdx.x & 15;
    if (n >= N) return;
    int start = offsets[n], end = start + deg[n];
    float ax = 0.f, ay = 0.f;
    if (sub == 0) { float2 s = h2p[n]; ax = s.x; ay = s.y; }   // self (pre-scaled)
    for (int j = start + sub; j < end; j += 16) {
        float2 v = h2p[scol[j]];
        ax += v.x; ay += v.y;
    }
#pragma unroll
    for (int s = 1; s <= 8; s <<= 1) {
        ax += __shfl_xor(ax, s, 64);
        ay += __shfl_xor(ay, s, 64);
    }
    if (sub == 0) {
        float dn = dinv[n];
        float l0 = fmaf(dn, ax, b2[0]), l1 = fmaf(dn, ay, b2[1]);
        float m = fmaxf(l0, l1);
        float e0 = __expf(l0 - m), e1 = __expf(l1 - m);
        float inv = 1.0f / (e0 + e1);
        out[n] = make_float2(e0 * inv, e1 * inv);
    }
}

extern "C" void kernel_launch(void* const* d_in, const int* in_sizes, int n_in,
                              void* d_out, int out_size, void* d_ws, size_t ws_size,
                              hipStream_t stream) {
    const float* x  = (const float*)d_in[0];
    const int*   ei = (const int*)d_in[1];
    const float* W1 = (const float*)d_in[2];
    const float* b1 = (const float*)d_in[3];
    const float* W2 = (const float*)d_in[4];
    const float* b2 = (const float*)d_in[5];
    float2* out = (float2*)d_out;

    const int N = in_sizes[0] / 64;     // 100000 (N%16==0, N<2^24)
    const int E = in_sizes[1] / 2;      // 1600000
    const int nb = (N + 127) >> 7;      // 782 buckets of 128 nodes
    const int SENT = nb << CAPSH;
    const int* row = ei;
    const int* col = ei + E;

    char* p = (char*)d_ws;
    auto alloc = [&](size_t bytes) -> void* {
        void* r = (void*)p;
        p += (bytes + 255) & ~(size_t)255;
        return r;
    };
    int*   relcur  = (int*)alloc((size_t)nb * 4);               // memset exact (R4 lesson)
    int*   offsets = (int*)alloc((size_t)(N + 1) * 4);
    int*   deg     = (int*)alloc((size_t)(N + 1) * 4);
    float* dinv    = (float*)alloc((size_t)N * 4);
    unsigned* pairbuf = (unsigned*)alloc((size_t)nb * CAP * 4);
    int*   scol    = (int*)alloc(((size_t)nb * CAP + 1) * 4);   // +1 sentinel
    __half* hp     = (__half*)alloc((size_t)(N + 1) * 64 * 2);  // +1 zero row
    float2* h2p    = (float2*)alloc((size_t)N * 8);

    const int nTile = (E + 4095) / 4096;  // 391

    hipMemsetAsync(relcur, 0, (size_t)nb * 4, stream);
    k_bin<<<nTile, 256, 0, stream>>>(row, col, relcur, pairbuf, hp, E, nb, N);
    k_sortgemm<<<nb, 256, 0, stream>>>(pairbuf, relcur, x, W1, scol, offsets, deg, dinv, hp, N, nb);
    const int nwaves = (N + 7) / 8;                  // 8 nodes per wave
    k_agg1<<<(nwaves + 3) / 4, 256, 0, stream>>>(hp, offsets, deg, scol, dinv, b1, W2, h2p, N, SENT);
    k_agg2<<<(N * 16 + 255) / 256, 256, 0, stream>>>(h2p, offsets, deg, scol, dinv, b2, out, N);
}